// Round 1
// baseline (3083.542 us; speedup 1.0000x reference)
//
#include <hip/hip_runtime.h>
#include <math.h>

#define VN 8192
#define DN 128
#define EN 262144
#define KD 512
#define KK (KD*KD)

// scalar slots
#define S_SS_LADJ 0
#define S_INV_C1  1
#define S_SS_S0   2
#define S_INV_C0  3
#define S_QRT_C0  4
#define S_SS_G    5
#define S_INV_CG  6
#define S_QRT_CG  7
#define S_TR_X    8
#define S_TR_S0   9
#define S_TR_YG   10

static __device__ __forceinline__ float waveReduceAdd(float v) {
#pragma unroll
  for (int o = 32; o; o >>= 1) v += __shfl_xor(v, o);
  return v;
}

// ---------- stage A: graph -> L_adj ----------

__global__ __launch_bounds__(256) void transpose_k(const float* __restrict__ in,
                                                   float* __restrict__ out) {
  // in: K x V, out: V x K
  __shared__ float s[32][33];
  int tx = threadIdx.x & 31, ty = threadIdx.x >> 5;
  int v0 = blockIdx.x * 32, k0 = blockIdx.y * 32;
  for (int r = ty; r < 32; r += 8) s[r][tx] = in[(size_t)(k0 + r) * VN + v0 + tx];
  __syncthreads();
  for (int r = ty; r < 32; r += 8) out[(size_t)(v0 + r) * KD + k0 + tx] = s[tx][r];
}

// one wave per edge: dedup (bitmap, first edge wins), distance+weight, degree counts
__global__ __launch_bounds__(256) void count_k(const float* __restrict__ x,
                                               const int* __restrict__ ei,
                                               int* __restrict__ ea, int* __restrict__ eb,
                                               float* __restrict__ ew,
                                               int* __restrict__ cnt,
                                               unsigned int* __restrict__ bitmap) {
  int e = (int)(((unsigned)blockIdx.x * 256u + threadIdx.x) >> 6);
  int lane = threadIdx.x & 63;
  if (e >= EN) return;
  int i = ei[e], j = ei[EN + e];
  int a = i < j ? i : j;
  int b = i < j ? j : i;
  int ok = 0;
  if (lane == 0) {
    if (i != j) {
      unsigned key = (unsigned)a * (unsigned)VN + (unsigned)b;
      unsigned m = 1u << (key & 31u);
      unsigned old = atomicOr(bitmap + (key >> 5), m);
      ok = (old & m) ? 0 : 1;
    }
  }
  ok = __shfl(ok, 0);
  if (!ok) { if (lane == 0) ea[e] = -1; return; }
  float d0 = x[a * DN + lane]      - x[b * DN + lane];
  float d1 = x[a * DN + 64 + lane] - x[b * DN + 64 + lane];
  float s = d0 * d0 + d1 * d1;
  s = waveReduceAdd(s);
  if (lane == 0) {
    ea[e] = a; eb[e] = b; ew[e] = expf(-s);
    atomicAdd(cnt + a, 1);
    atomicAdd(cnt + b, 1);
  }
}

__global__ __launch_bounds__(1024) void scan_k(const int* __restrict__ cnt,
                                               int* __restrict__ rowptr,
                                               int* __restrict__ cursor) {
  __shared__ int sd[1024];
  __shared__ int carry;
  int tid = threadIdx.x;
  if (tid == 0) { carry = 0; rowptr[0] = 0; }
  __syncthreads();
  for (int c = 0; c < VN / 1024; ++c) {
    int v = c * 1024 + tid;
    int xv = cnt[v];
    sd[tid] = xv;
    __syncthreads();
    for (int off = 1; off < 1024; off <<= 1) {
      int t = (tid >= off) ? sd[tid - off] : 0;
      __syncthreads();
      sd[tid] += t;
      __syncthreads();
    }
    int incl = sd[tid];
    int base = carry;
    rowptr[v + 1] = base + incl;
    cursor[v] = base + incl - xv;
    __syncthreads();
    if (tid == 1023) carry = base + incl;
    __syncthreads();
  }
}

__global__ __launch_bounds__(256) void fill_k(const int* __restrict__ ea, const int* __restrict__ eb,
                                              const float* __restrict__ ew,
                                              int* __restrict__ cursor,
                                              int* __restrict__ adjj, float* __restrict__ adjw) {
  int e = blockIdx.x * 256 + threadIdx.x;
  if (e >= EN) return;
  int a = ea[e];
  if (a < 0) return;
  int b = eb[e];
  float w = ew[e];
  int p = atomicAdd(cursor + a, 1); adjj[p] = b; adjw[p] = w;
  int q = atomicAdd(cursor + b, 1); adjj[q] = a; adjw[q] = w;
}

// B[v,k] = d'_v * pmatT[v,k] - sum_{j in N(v)} w * pmatT[j,k]
__global__ __launch_bounds__(512) void buildB_k(const float* __restrict__ pmatT,
                                                const int* __restrict__ rowptr,
                                                const int* __restrict__ adjj,
                                                const float* __restrict__ adjw,
                                                float* __restrict__ Bout) {
  int v = blockIdx.x;
  int k = threadIdx.x;
  int s = rowptr[v], e = rowptr[v + 1];
  float acc = 0.f, sw = 0.f;
  for (int p = s; p < e; ++p) {
    int jj = adjj[p];
    float w = adjw[p];
    acc += w * pmatT[jj * KD + k];
    sw += w;
  }
  Bout[v * KD + k] = sw * pmatT[v * KD + k] - acc;
}

// C(512x512) += pmat(512x8192) @ B(8192x512), split-k over blockIdx.z (8 slices)
__global__ __launch_bounds__(256) void gemm_big_k(const float* __restrict__ A,
                                                  const float* __restrict__ B,
                                                  float* __restrict__ C) {
  __shared__ __align__(16) float As[32][34];
  __shared__ __align__(16) float Bs[32][34];
  int tid = threadIdx.x;
  int tx = tid & 15, ty = tid >> 4;
  int n0 = blockIdx.x * 32, m0 = blockIdx.y * 32;
  int kbase = blockIdx.z * (VN / 8);
  float a00 = 0.f, a01 = 0.f, a10 = 0.f, a11 = 0.f;
  for (int kt = kbase; kt < kbase + VN / 8; kt += 32) {
#pragma unroll
    for (int u = 0; u < 4; ++u) {
      int li = tid * 4 + u;
      int r = li >> 5, c = li & 31;
      As[c][r] = A[(size_t)(m0 + r) * VN + kt + c];
      Bs[r][c] = B[(size_t)(kt + r) * KD + n0 + c];
    }
    __syncthreads();
#pragma unroll
    for (int k = 0; k < 32; ++k) {
      float2 av = *(const float2*)&As[k][2 * ty];
      float2 bv = *(const float2*)&Bs[k][2 * tx];
      a00 += av.x * bv.x; a01 += av.x * bv.y;
      a10 += av.y * bv.x; a11 += av.y * bv.y;
    }
    __syncthreads();
  }
  int m = m0 + 2 * ty, n = n0 + 2 * tx;
  atomicAdd(&C[m * KD + n], a00);
  atomicAdd(&C[m * KD + n + 1], a01);
  atomicAdd(&C[(m + 1) * KD + n], a10);
  atomicAdd(&C[(m + 1) * KD + n + 1], a11);
}

// ---------- generic 512x512 GEMM: C = alpha*(A@B) + beta*Dm ----------

static __device__ __forceinline__ void gemm_body(const float* __restrict__ A,
                                                 const float* __restrict__ B,
                                                 const float* __restrict__ Dm,
                                                 float* __restrict__ C,
                                                 float alpha, float beta) {
  __shared__ __align__(16) float As[32][34];
  __shared__ __align__(16) float Bs[32][34];
  int tid = threadIdx.x;
  int tx = tid & 15, ty = tid >> 4;
  int n0 = blockIdx.x * 32, m0 = blockIdx.y * 32;
  float a00 = 0.f, a01 = 0.f, a10 = 0.f, a11 = 0.f;
  for (int kt = 0; kt < KD; kt += 32) {
#pragma unroll
    for (int u = 0; u < 4; ++u) {
      int li = tid * 4 + u;
      int r = li >> 5, c = li & 31;
      As[c][r] = A[(m0 + r) * KD + kt + c];
      Bs[r][c] = B[(kt + r) * KD + n0 + c];
    }
    __syncthreads();
#pragma unroll
    for (int k = 0; k < 32; ++k) {
      float2 av = *(const float2*)&As[k][2 * ty];
      float2 bv = *(const float2*)&Bs[k][2 * tx];
      a00 += av.x * bv.x; a01 += av.x * bv.y;
      a10 += av.y * bv.x; a11 += av.y * bv.y;
    }
    __syncthreads();
  }
  int m = m0 + 2 * ty, n = n0 + 2 * tx;
  float d00 = 0.f, d01 = 0.f, d10 = 0.f, d11 = 0.f;
  if (beta != 0.0f) {
    d00 = Dm[m * KD + n];       d01 = Dm[m * KD + n + 1];
    d10 = Dm[(m + 1) * KD + n]; d11 = Dm[(m + 1) * KD + n + 1];
  }
  C[m * KD + n]           = alpha * a00 + beta * d00;
  C[m * KD + n + 1]       = alpha * a01 + beta * d01;
  C[(m + 1) * KD + n]     = alpha * a10 + beta * d10;
  C[(m + 1) * KD + n + 1] = alpha * a11 + beta * d11;
}

__global__ __launch_bounds__(256) void gemm_kk(const float* __restrict__ A,
                                               const float* __restrict__ B,
                                               const float* __restrict__ Dm,
                                               float* __restrict__ C,
                                               float alpha, float beta) {
  gemm_body(A, B, Dm, C, alpha, beta);
}

// two independent GEMMs in one launch (blockIdx.z picks), same alpha/beta
__global__ __launch_bounds__(256) void gemm_dual(const float* A0, const float* B0,
                                                 const float* D0, float* C0,
                                                 const float* A1, const float* B1,
                                                 const float* D1, float* C1,
                                                 float alpha, float beta) {
  if (blockIdx.z == 0) gemm_body(A0, B0, D0, C0, alpha, beta);
  else                 gemm_body(A1, B1, D1, C1, alpha, beta);
}

// ---------- small utility kernels ----------

__global__ __launch_bounds__(256) void sumsq_k(const float* __restrict__ A, int n,
                                               float* __restrict__ slot) {
  float s = 0.f;
  for (int i = blockIdx.x * 256 + threadIdx.x; i < n; i += gridDim.x * 256) {
    float v = A[i];
    s += v * v;
  }
  __shared__ float p[4];
  s = waveReduceAdd(s);
  if ((threadIdx.x & 63) == 0) p[threadIdx.x >> 6] = s;
  __syncthreads();
  if (threadIdx.x == 0) atomicAdd(slot, p[0] + p[1] + p[2] + p[3]);
}

__global__ __launch_bounds__(512) void trace_k(const float* __restrict__ A,
                                               float* __restrict__ slot) {
  float v = A[(size_t)threadIdx.x * KD + threadIdx.x];
  __shared__ float p[8];
  v = waveReduceAdd(v);
  if ((threadIdx.x & 63) == 0) p[threadIdx.x >> 6] = v;
  __syncthreads();
  if (threadIdx.x == 0) {
    float t = 0.f;
    for (int i = 0; i < 8; ++i) t += p[i];
    slot[0] = t;
  }
}

__global__ void derive_k(const float* __restrict__ in, float* __restrict__ o_rsqrt,
                         float* __restrict__ o_qroot) {
  float x = in[0];
  o_rsqrt[0] = 1.0f / sqrtf(x);        // 1 / ||.||_F
  if (o_qroot) o_qroot[0] = powf(x, 0.25f);  // sqrt(||.||_F)
}

__global__ __launch_bounds__(256) void setid_const_k(float* __restrict__ C, float val) {
  int idx = blockIdx.x * 256 + threadIdx.x;
  if (idx >= KK) return;
  int r = idx >> 9, c = idx & (KD - 1);
  C[idx] = (r == c) ? val : 0.0f;
}

__global__ __launch_bounds__(256) void setid_dev_k(float* __restrict__ C,
                                                   const float* __restrict__ s) {
  int idx = blockIdx.x * 256 + threadIdx.x;
  if (idx >= KK) return;
  int r = idx >> 9, c = idx & (KD - 1);
  C[idx] = (r == c) ? s[0] : 0.0f;
}

__global__ __launch_bounds__(256) void scale_k(const float* __restrict__ A,
                                               const float* __restrict__ s,
                                               float* __restrict__ C) {
  int idx = blockIdx.x * 256 + threadIdx.x;
  if (idx >= KK) return;
  C[idx] = A[idx] * s[0];
}

__global__ __launch_bounds__(256) void sym_k(const float* __restrict__ G,
                                             float* __restrict__ Out) {
  int idx = blockIdx.x * 256 + threadIdx.x;
  if (idx >= KK) return;
  int r = idx >> 9, c = idx & (KD - 1);
  Out[idx] = 0.5f * (G[idx] + G[c * KD + r]);
}

__global__ void final_k(const float* __restrict__ scal, float* __restrict__ out) {
  // out = tr(S1) + tr(S0) - 2 * sqrt(cG) * tr(Y_G)
  out[0] = scal[S_TR_X] + scal[S_TR_S0] - 2.0f * scal[S_QRT_CG] * scal[S_TR_YG];
}

// ---------- host ----------

extern "C" void kernel_launch(void* const* d_in, const int* in_sizes, int n_in,
                              void* d_out, int out_size, void* d_ws, size_t ws_size,
                              hipStream_t stream) {
  (void)in_sizes; (void)n_in; (void)out_size; (void)ws_size;
  const float* x    = (const float*)d_in[0];  // V x D
  const float* S0   = (const float*)d_in[1];  // K x K (targets)
  const int*   ei   = (const int*)d_in[2];    // 2 x E
  const float* pmat = (const float*)d_in[3];  // K x V
  float* out = (float*)d_out;
  char* ws = (char*)d_ws;

  size_t off = 0;
  unsigned* bitmap = (unsigned*)(ws + off); off += (size_t)VN * VN / 8;       // 8 MB
  size_t off_pool = off;                                                      // pool overlays pmatT
  float* pmatT = (float*)(ws + off); off += (size_t)VN * KD * 4;              // 16 MB
  float* Bm    = (float*)(ws + off); off += (size_t)VN * KD * 4;              // 16 MB
  int*   ea    = (int*)(ws + off);   off += (size_t)EN * 4;
  int*   eb    = (int*)(ws + off);   off += (size_t)EN * 4;
  float* ew    = (float*)(ws + off); off += (size_t)EN * 4;
  int*   cnt   = (int*)(ws + off);   off += (size_t)VN * 4;
  int*  rowptr = (int*)(ws + off);   off += (size_t)(VN + 2) * 4;
  int*  cursor = (int*)(ws + off);   off += (size_t)VN * 4;
  int*   adjj  = (int*)(ws + off);   off += (size_t)2 * EN * 4;
  float* adjw  = (float*)(ws + off); off += (size_t)2 * EN * 4;
  float* scal  = (float*)(ws + off); off += 64 * 4;

  // K x K pool (12 MB), overlays pmatT region: pmatT is dead before first pool write
  float* P[12];
  for (int i = 0; i < 12; ++i) P[i] = (float*)(ws + off_pool + (size_t)i * KK * 4);
  float* Ladj = P[0];
  float* Xa = P[1]; float* Xb = P[2]; float* U = P[3];
  float* Ya = P[4]; float* Yb = P[5]; float* Za = P[6]; float* Zb = P[7];
  float* Pm = P[8]; float* S0h = P[9]; float* TMP = P[10]; float* G = P[11];

  // zero accumulator state (every call -> deterministic)
  hipMemsetAsync(bitmap, 0, (size_t)VN * VN / 8, stream);
  hipMemsetAsync(cnt, 0, (size_t)VN * 4, stream);
  hipMemsetAsync(scal, 0, 64 * 4, stream);

  // stage A: graph construction -> L_adj
  transpose_k<<<dim3(VN / 32, KD / 32), 256, 0, stream>>>(pmat, pmatT);
  count_k<<<EN / 4, 256, 0, stream>>>(x, ei, ea, eb, ew, cnt, bitmap);
  scan_k<<<1, 1024, 0, stream>>>(cnt, rowptr, cursor);
  fill_k<<<EN / 256, 256, 0, stream>>>(ea, eb, ew, cursor, adjj, adjw);
  buildB_k<<<VN, 512, 0, stream>>>(pmatT, rowptr, adjj, adjw, Bm);
  setid_const_k<<<KK / 256, 256, 0, stream>>>(Ladj, 1e-5f);
  gemm_big_k<<<dim3(16, 16, 8), 256, 0, stream>>>(pmat, Bm, Ladj);

  // stage B: S1 = inv(L_adj) via Newton-Schulz, X0 = I/||A||_F
  sumsq_k<<<256, 256, 0, stream>>>(Ladj, KK, &scal[S_SS_LADJ]);
  derive_k<<<1, 1, 0, stream>>>(&scal[S_SS_LADJ], &scal[S_INV_C1], nullptr);
  setid_dev_k<<<KK / 256, 256, 0, stream>>>(Xa, &scal[S_INV_C1]);
  for (int it = 0; it < 24; ++it) {
    gemm_kk<<<dim3(16, 16), 256, 0, stream>>>(Ladj, Xa, nullptr, U, 1.0f, 0.0f);
    gemm_kk<<<dim3(16, 16), 256, 0, stream>>>(Xa, U, Xa, Xb, -1.0f, 2.0f);
    float* t = Xa; Xa = Xb; Xb = t;
  }
  trace_k<<<1, 512, 0, stream>>>(Xa, &scal[S_TR_X]);

  // stage C: S0_sqrt = sqrtm(targets) via coupled Newton-Schulz
  sumsq_k<<<256, 256, 0, stream>>>(S0, KK, &scal[S_SS_S0]);
  derive_k<<<1, 1, 0, stream>>>(&scal[S_SS_S0], &scal[S_INV_C0], &scal[S_QRT_C0]);
  scale_k<<<KK / 256, 256, 0, stream>>>(S0, &scal[S_INV_C0], Ya);
  setid_const_k<<<KK / 256, 256, 0, stream>>>(Za, 1.0f);
  for (int it = 0; it < 18; ++it) {
    gemm_kk<<<dim3(16, 16), 256, 0, stream>>>(Za, Ya, nullptr, Pm, 1.0f, 0.0f);
    gemm_dual<<<dim3(16, 16, 2), 256, 0, stream>>>(Ya, Pm, Ya, Yb,
                                                   Pm, Za, Za, Zb, -0.5f, 1.5f);
    float* t = Ya; Ya = Yb; Yb = t;
    t = Za; Za = Zb; Zb = t;
  }
  scale_k<<<KK / 256, 256, 0, stream>>>(Ya, &scal[S_QRT_C0], S0h);
  trace_k<<<1, 512, 0, stream>>>(S0, &scal[S_TR_S0]);

  // stage D: G = S0h @ S1 @ S0h (symmetrized), then tr(sqrtm(G))
  gemm_kk<<<dim3(16, 16), 256, 0, stream>>>(S0h, Xa, nullptr, TMP, 1.0f, 0.0f);
  gemm_kk<<<dim3(16, 16), 256, 0, stream>>>(TMP, S0h, nullptr, G, 1.0f, 0.0f);
  sym_k<<<KK / 256, 256, 0, stream>>>(G, TMP);  // TMP = (G + G^T)/2
  sumsq_k<<<256, 256, 0, stream>>>(TMP, KK, &scal[S_SS_G]);
  derive_k<<<1, 1, 0, stream>>>(&scal[S_SS_G], &scal[S_INV_CG], &scal[S_QRT_CG]);
  scale_k<<<KK / 256, 256, 0, stream>>>(TMP, &scal[S_INV_CG], Ya);
  setid_const_k<<<KK / 256, 256, 0, stream>>>(Za, 1.0f);
  for (int it = 0; it < 26; ++it) {
    gemm_kk<<<dim3(16, 16), 256, 0, stream>>>(Za, Ya, nullptr, Pm, 1.0f, 0.0f);
    gemm_dual<<<dim3(16, 16, 2), 256, 0, stream>>>(Ya, Pm, Ya, Yb,
                                                   Pm, Za, Za, Zb, -0.5f, 1.5f);
    float* t = Ya; Ya = Yb; Yb = t;
    t = Za; Za = Zb; Zb = t;
  }
  trace_k<<<1, 512, 0, stream>>>(Ya, &scal[S_TR_YG]);

  final_k<<<1, 1, 0, stream>>>(scal, out);
}